// Round 5
// baseline (549.137 us; speedup 1.0000x reference)
//
#include <hip/hip_runtime.h>

typedef unsigned short u16;
typedef __attribute__((ext_vector_type(8))) short bf16x8v;
typedef __attribute__((ext_vector_type(4))) float f32x4v;

#define B_SZ 16384
#define F_SZ 50
#define E_SZ 64
#define D_SZ 512
#define H1_SZ 1024
#define H2_SZ 512
#define KP 4096   // padded product-layer K: (e*64+f), f padded 50->64
#define LP_NB 16  // b's per k_lp block; grid = B_SZ/LP_NB

__device__ __forceinline__ float b2f(u16 u){
  union { unsigned int i; float f; } v; v.i = ((unsigned int)u) << 16; return v.f;
}
__device__ __forceinline__ u16 f2b(float f){
  union { float f; unsigned int i; } v; v.f = f;
  unsigned int r = v.i + 0x7FFFu + ((v.i >> 16) & 1u);
  return (u16)(r >> 16);
}

// async global->LDS, 16B/lane. g is per-lane (base + lane*16B); lds base is
// wave-uniform; HW writes lds_base + lane*16.
__device__ __forceinline__ void gload16(const u16* g, u16* lds_base_uniform){
#if __has_builtin(__builtin_amdgcn_global_load_lds)
  __builtin_amdgcn_global_load_lds(
      (const __attribute__((address_space(1))) unsigned int*)g,
      (__attribute__((address_space(3))) unsigned int*)lds_base_uniform,
      16, 0, 0);
#else
  int lane = threadIdx.x & 63;
  *(uint4*)(lds_base_uniform + lane*8) = *(const uint4*)g;
#endif
}

// ---------------- gather: embT[b][e*64+f] = fe[idx[b,f],e]*fv[b,f] (bf16), f>=50 -> 0
__global__ __launch_bounds__(256) void k_gather(
    const int* __restrict__ fidx, const float* __restrict__ fval,
    const float* __restrict__ femb, u16* __restrict__ embT)
{
  __shared__ int   sidx[F_SZ];
  __shared__ float sfv[F_SZ];
  __shared__ u16   tile[F_SZ*66];   // padded stride 66 to break bank conflicts
  const int b = blockIdx.x, t = threadIdx.x;
  if (t < F_SZ){ sidx[t] = fidx[b*F_SZ+t]; sfv[t] = fval[b*F_SZ+t]; }
  __syncthreads();
  #pragma unroll
  for (int i=0;i<13;i++){
    int k = i*256+t;
    if (k < F_SZ*E_SZ){
      int f = k>>6, e = k&63;
      tile[f*66+e] = f2b(femb[(size_t)sidx[f]*E_SZ + e] * sfv[f]);
    }
  }
  __syncthreads();
  u16* orow = embT + (size_t)b*KP;
  #pragma unroll
  for (int i=0;i<16;i++){
    int k = i*256+t;           // k = e*64+f
    int f = k&63, e = k>>6;
    orow[k] = (f < F_SZ) ? tile[f*66+e] : (u16)0;
  }
}

// ---------------- product_linear (D,F,E) fp32 -> WlT (D, e*64+f) bf16 zero-padded
__global__ __launch_bounds__(256) void k_wlt(const float* __restrict__ Wl, u16* __restrict__ WlT)
{
  __shared__ u16 tile[F_SZ*66];
  const int d = blockIdx.x, t = threadIdx.x;
  #pragma unroll
  for (int i=0;i<13;i++){
    int k = i*256+t;
    if (k < F_SZ*E_SZ) tile[(k>>6)*66 + (k&63)] = f2b(Wl[(size_t)d*(F_SZ*E_SZ) + k]);
  }
  __syncthreads();
  u16* orow = WlT + (size_t)d*KP;
  #pragma unroll
  for (int i=0;i<16;i++){
    int k = i*256+t;
    int f = k&63, e = k>>6;
    orow[k] = (f < F_SZ) ? tile[f*66+e] : (u16)0;
  }
}

// ---------------- product_quadratic_inner (D,F) fp32 -> PqTp (D,64) bf16 padded
__global__ void k_pqt(const float* __restrict__ Pq, u16* __restrict__ PqTp){
  int idx = blockIdx.x*256 + threadIdx.x;   // grid 128 -> 32768
  int d = idx >> 6, f = idx & 63;
  PqTp[idx] = (f < F_SZ) ? f2b(Pq[d*F_SZ + f]) : (u16)0;
}

// ---------------- (K,N) fp32 -> (N,K) bf16 transpose for dense weights
__global__ void k_transpose(const float* __restrict__ W, u16* __restrict__ WT,
                            int klog2, int N, int total){
  int idx = blockIdx.x*256 + threadIdx.x;
  if (idx < total){
    int k = idx & ((1<<klog2)-1), n = idx >> klog2;
    WT[idx] = f2b(W[(size_t)k*N + n]);
  }
}

// ---------------- cvec[h] += sum_{d in chunk} pbias[d]*W0[d][h] (+ b0[h] once)
// grid (4, 8), block 256; cvec pre-zeroed by memset.
__global__ __launch_bounds__(256) void k_cvec(
    const float* __restrict__ pb, const float* __restrict__ W0,
    const float* __restrict__ b0, float* __restrict__ cvec)
{
  int h = blockIdx.x*256 + threadIdx.x;
  int d0 = blockIdx.y*64;
  float acc = (blockIdx.y == 0) ? b0[h] : 0.f;
  #pragma unroll 8
  for (int d=0; d<64; d++) acc += pb[d0+d]*W0[(size_t)(d0+d)*H1_SZ + h];
  atomicAdd(&cvec[h], acc);
}

// ---------------- m97-style BT GEMM: C(MxN) = A(MxK) * Bm(NxK)^T, bf16 inputs
// DO_STATS: add fp32 bias[n], atomically accumulate per-column sum/sumsq.
template<int DO_STATS, typename CT>
__global__ __launch_bounds__(256) void gemm_bt(
    const u16* __restrict__ A, const u16* __restrict__ Bm,
    CT* __restrict__ C, const float* __restrict__ bias,
    float* __restrict__ S1, float* __restrict__ S2,
    int M, int N, int K)
{
  __shared__ __align__(16) u16 As[128*64];
  __shared__ __align__(16) u16 Bs[128*64];
  const int tid  = threadIdx.x;
  const int wave = tid >> 6, lane = tid & 63;
  const int quad = lane >> 4, l16 = lane & 15;
  const int n0 = blockIdx.x * 128, m0 = blockIdx.y * 128;
  const int wr = wave >> 1, wc = wave & 1;
  const int lr = lane >> 3, lc = (lane & 7) * 8;

  f32x4v acc[4][4];
  #pragma unroll
  for (int i=0;i<4;i++)
    #pragma unroll
    for (int j=0;j<4;j++)
      acc[i][j] = (f32x4v){0.f,0.f,0.f,0.f};

  for (int k0 = 0; k0 < K; k0 += 64){
    __syncthreads();
    #pragma unroll
    for (int c=0;c<4;c++){
      const int r0 = wave*32 + 8*c;          // 8 rows per 16B-call
      gload16(A  + (size_t)(m0 + r0 + lr)*K + k0 + lc, As + r0*64);
      gload16(Bm + (size_t)(n0 + r0 + lr)*K + k0 + lc, Bs + r0*64);
    }
    __syncthreads();
    #pragma unroll
    for (int ks=0; ks<2; ks++){
      bf16x8v af[4], bfr[4];
      #pragma unroll
      for (int mt=0;mt<4;mt++)
        af[mt] = *(const bf16x8v*)&As[(wr*64+mt*16+l16)*64 + ks*32 + quad*8];
      #pragma unroll
      for (int nt=0;nt<4;nt++)
        bfr[nt] = *(const bf16x8v*)&Bs[(wc*64+nt*16+l16)*64 + ks*32 + quad*8];
      #pragma unroll
      for (int mt=0;mt<4;mt++)
        #pragma unroll
        for (int nt=0;nt<4;nt++)
          acc[mt][nt] = __builtin_amdgcn_mfma_f32_16x16x32_bf16(af[mt], bfr[nt], acc[mt][nt], 0, 0, 0);
    }
  }

  // epilogue; C/D layout: n = lane&15, m = quad*4 + reg
  #pragma unroll
  for (int nt=0;nt<4;nt++){
    const int n = n0 + wc*64 + nt*16 + l16;
    float bv = 0.f;
    if (DO_STATS) bv = bias[n];
    float ls1 = 0.f, ls2 = 0.f;
    #pragma unroll
    for (int mt=0;mt<4;mt++){
      const int mb = m0 + wr*64 + mt*16 + quad*4;
      #pragma unroll
      for (int r=0;r<4;r++){
        float v = acc[mt][nt][r] + bv;
        if constexpr (sizeof(CT) == 2) C[(size_t)(mb+r)*N + n] = f2b(v);
        else                           C[(size_t)(mb+r)*N + n] = v;
        ls1 += v; ls2 += v*v;
      }
    }
    if (DO_STATS){
      ls1 += __shfl_xor(ls1, 16); ls2 += __shfl_xor(ls2, 16);
      ls1 += __shfl_xor(ls1, 32); ls2 += __shfl_xor(ls2, 32);
      if (quad == 0){ atomicAdd(&S1[n], ls1); atomicAdd(&S2[n], ls2); }
    }
  }
}

// ---------------- split-K BT GEMM for lz: grid (N/128, M/128, 2); each z-slice
// does K/2 and atomically adds fp32 partials into C (pre-zeroed).
__global__ __launch_bounds__(256) void gemm_bt_sk(
    const u16* __restrict__ A, const u16* __restrict__ Bm,
    float* __restrict__ C, int N, int K)
{
  __shared__ __align__(16) u16 As[128*64];
  __shared__ __align__(16) u16 Bs[128*64];
  const int tid  = threadIdx.x;
  const int wave = tid >> 6, lane = tid & 63;
  const int quad = lane >> 4, l16 = lane & 15;
  const int n0 = blockIdx.x * 128, m0 = blockIdx.y * 128;
  const int kbase = blockIdx.z * (K >> 1), kend = kbase + (K >> 1);
  const int wr = wave >> 1, wc = wave & 1;
  const int lr = lane >> 3, lc = (lane & 7) * 8;

  f32x4v acc[4][4];
  #pragma unroll
  for (int i=0;i<4;i++)
    #pragma unroll
    for (int j=0;j<4;j++)
      acc[i][j] = (f32x4v){0.f,0.f,0.f,0.f};

  for (int k0 = kbase; k0 < kend; k0 += 64){
    __syncthreads();
    #pragma unroll
    for (int c=0;c<4;c++){
      const int r0 = wave*32 + 8*c;
      gload16(A  + (size_t)(m0 + r0 + lr)*K + k0 + lc, As + r0*64);
      gload16(Bm + (size_t)(n0 + r0 + lr)*K + k0 + lc, Bs + r0*64);
    }
    __syncthreads();
    #pragma unroll
    for (int ks=0; ks<2; ks++){
      bf16x8v af[4], bfr[4];
      #pragma unroll
      for (int mt=0;mt<4;mt++)
        af[mt] = *(const bf16x8v*)&As[(wr*64+mt*16+l16)*64 + ks*32 + quad*8];
      #pragma unroll
      for (int nt=0;nt<4;nt++)
        bfr[nt] = *(const bf16x8v*)&Bs[(wc*64+nt*16+l16)*64 + ks*32 + quad*8];
      #pragma unroll
      for (int mt=0;mt<4;mt++)
        #pragma unroll
        for (int nt=0;nt<4;nt++)
          acc[mt][nt] = __builtin_amdgcn_mfma_f32_16x16x32_bf16(af[mt], bfr[nt], acc[mt][nt], 0, 0, 0);
    }
  }

  #pragma unroll
  for (int nt=0;nt<4;nt++){
    const int n = n0 + wc*64 + nt*16 + l16;
    #pragma unroll
    for (int mt=0;mt<4;mt++){
      const int mb = m0 + wr*64 + mt*16 + quad*4;
      #pragma unroll
      for (int r=0;r<4;r++)
        atomicAdd(&C[(size_t)(mb+r)*N + n], acc[mt][nt][r]);
    }
  }
}

// ---------------- quadratic-inner v4: LDS-free, register-resident P^T, 128 d/wave.
// Block (4 waves) covers all 512 d; grid = B/LP_NB blocks. Tiles TRANSPOSED
// (rows=e from embT, cols=d); ps loop-invariant in VGPRs; A frags per-lane
// 16B global loads (shared by 4 waves -> L1 hits). No LDS, no barriers.
__global__ __launch_bounds__(256, 2) void k_lp(
    const u16* __restrict__ embT, const u16* __restrict__ PqTp,
    const float* __restrict__ lzf, const float* __restrict__ pbias,
    u16* __restrict__ y0)
{
  const int tid  = threadIdx.x;
  const int wave = tid >> 6, lane = tid & 63;
  const int quad = lane >> 4, l16 = lane & 15;
  const int dwave = wave * 128;               // this wave's 128 d's
  const int b0    = blockIdx.x * LP_NB;

  // loop-invariant B-operand fragments (8 nt x 2 ks) = 64 VGPR
  bf16x8v ps[8][2];
  #pragma unroll
  for (int nt=0;nt<8;nt++)
    #pragma unroll
    for (int ks=0;ks<2;ks++)
      ps[nt][ks] = *(const bf16x8v*)&PqTp[(dwave + nt*16 + l16)*64 + ks*32 + quad*8];

  const int dme0 = dwave + lane, dme1 = dme0 + 64;   // lane -> d (coalesced)
  const float pb0 = pbias[dme0], pb1 = pbias[dme1];

  bf16x8v afA[8], afB[8];            // A fragments, ping-pong [ks*4+mt]
  {
    const u16* g = embT + (size_t)b0*KP;
    #pragma unroll
    for (int ks=0;ks<2;ks++)
      #pragma unroll
      for (int mt=0;mt<4;mt++)
        afA[ks*4+mt] = *(const bf16x8v*)&g[(mt*16+l16)*64 + ks*32 + quad*8];
  }

  #pragma unroll 1
  for (int i=0;i<LP_NB;i+=2){
    // prefetch b0+i+1 into afB
    {
      const u16* g = embT + (size_t)(b0+i+1)*KP;
      #pragma unroll
      for (int ks=0;ks<2;ks++)
        #pragma unroll
        for (int mt=0;mt<4;mt++)
          afB[ks*4+mt] = *(const bf16x8v*)&g[(mt*16+l16)*64 + ks*32 + quad*8];
    }
    // compute for b0+i with afA
    #pragma unroll 1
    for (int half=0; half<1; half++){
      const int b = b0+i;
      float v[8];
      #pragma unroll
      for (int nt=0;nt<8;nt++){
        f32x4v acc[4];
        #pragma unroll
        for (int mt=0;mt<4;mt++) acc[mt] = (f32x4v){0.f,0.f,0.f,0.f};
        #pragma unroll
        for (int ks=0;ks<2;ks++)
          #pragma unroll
          for (int mt=0;mt<4;mt++)
            acc[mt] = __builtin_amdgcn_mfma_f32_16x16x32_bf16(afA[ks*4+mt], ps[nt][ks], acc[mt], 0,0,0);
        float s = 0.f;
        #pragma unroll
        for (int mt=0;mt<4;mt++)
          #pragma unroll
          for (int r=0;r<4;r++)
            s = fmaf(acc[mt][r], acc[mt][r], s);
        s += __shfl_xor(s, 16);
        s += __shfl_xor(s, 32);
        v[nt] = s;                   // lp^2 for d = dwave + nt*16 + l16
      }
      float t01 = (quad & 1) ? v[1] : v[0];
      float t23 = (quad & 1) ? v[3] : v[2];
      float vlo = (quad & 2) ? t23 : t01;
      float t45 = (quad & 1) ? v[5] : v[4];
      float t67 = (quad & 1) ? v[7] : v[6];
      float vhi = (quad & 2) ? t67 : t45;
      float y0v = lzf[(size_t)b*D_SZ + dme0] + sqrtf(vlo) + pb0;
      float y1v = lzf[(size_t)b*D_SZ + dme1] + sqrtf(vhi) + pb1;
      y0v = (y0v > 0.f ? y0v : 0.f) - pb0;
      y1v = (y1v > 0.f ? y1v : 0.f) - pb1;
      y0[(size_t)b*D_SZ + dme0] = f2b(y0v);
      y0[(size_t)b*D_SZ + dme1] = f2b(y1v);
    }
    // prefetch b0+i+2 into afA
    if (i+2 < LP_NB){
      const u16* g = embT + (size_t)(b0+i+2)*KP;
      #pragma unroll
      for (int ks=0;ks<2;ks++)
        #pragma unroll
        for (int mt=0;mt<4;mt++)
          afA[ks*4+mt] = *(const bf16x8v*)&g[(mt*16+l16)*64 + ks*32 + quad*8];
    }
    // compute for b0+i+1 with afB
    #pragma unroll 1
    for (int half=0; half<1; half++){
      const int b = b0+i+1;
      float v[8];
      #pragma unroll
      for (int nt=0;nt<8;nt++){
        f32x4v acc[4];
        #pragma unroll
        for (int mt=0;mt<4;mt++) acc[mt] = (f32x4v){0.f,0.f,0.f,0.f};
        #pragma unroll
        for (int ks=0;ks<2;ks++)
          #pragma unroll
          for (int mt=0;mt<4;mt++)
            acc[mt] = __builtin_amdgcn_mfma_f32_16x16x32_bf16(afB[ks*4+mt], ps[nt][ks], acc[mt], 0,0,0);
        float s = 0.f;
        #pragma unroll
        for (int mt=0;mt<4;mt++)
          #pragma unroll
          for (int r=0;r<4;r++)
            s = fmaf(acc[mt][r], acc[mt][r], s);
        s += __shfl_xor(s, 16);
        s += __shfl_xor(s, 32);
        v[nt] = s;
      }
      float t01 = (quad & 1) ? v[1] : v[0];
      float t23 = (quad & 1) ? v[3] : v[2];
      float vlo = (quad & 2) ? t23 : t01;
      float t45 = (quad & 1) ? v[5] : v[4];
      float t67 = (quad & 1) ? v[7] : v[6];
      float vhi = (quad & 2) ? t67 : t45;
      float y0v = lzf[(size_t)b*D_SZ + dme0] + sqrtf(vlo) + pb0;
      float y1v = lzf[(size_t)b*D_SZ + dme1] + sqrtf(vhi) + pb1;
      y0v = (y0v > 0.f ? y0v : 0.f) - pb0;
      y1v = (y1v > 0.f ? y1v : 0.f) - pb1;
      y0[(size_t)b*D_SZ + dme0] = f2b(y0v);
      y0[(size_t)b*D_SZ + dme1] = f2b(y1v);
    }
  }
}

// ---------------- BN finalize: per-column scale/offset from sums
__global__ void k_bnfin(const float* __restrict__ S1, const float* __restrict__ S2, int n,
                        const float* __restrict__ bnsc, const float* __restrict__ bnof,
                        float* __restrict__ Aout, float* __restrict__ Bout)
{
  int i = blockIdx.x*256 + threadIdx.x;
  if (i < n){
    const float invB = 1.f / 16384.f;
    float m   = S1[i]*invB;
    float var = S2[i]*invB - m*m;
    float a   = bnsc[0] * rsqrtf(var + 1e-10f);
    Aout[i] = a;
    Bout[i] = bnof[0] - m*a;
  }
}

// ---------------- BN apply + relu: fp32 Z in, bf16 Y out, 8 elems/thread
__global__ __launch_bounds__(256) void k_bnapply(
    const float* __restrict__ Z, u16* __restrict__ Y,
    const float* __restrict__ Aa, const float* __restrict__ Bb, int nmask)
{
  size_t base = ((size_t)blockIdx.x*256 + threadIdx.x) * 8;
  int n0 = (int)(base & (size_t)nmask);
  float4 za = *(const float4*)&Z[base];
  float4 zb = *(const float4*)&Z[base+4];
  float zz[8] = {za.x,za.y,za.z,za.w,zb.x,zb.y,zb.z,zb.w};
  union { uint4 q; u16 s[8]; } o;
  #pragma unroll
  for (int j=0;j<8;j++){
    float v = zz[j] * Aa[n0+j] + Bb[n0+j];
    o.s[j] = f2b(v > 0.f ? v : 0.f);
  }
  *(uint4*)&Y[base] = o.q;
}

// ---------------- final dot + sigmoid, one wave per row; fp32 w and out
__global__ __launch_bounds__(256) void k_out(
    const u16* __restrict__ Y2, const float* __restrict__ wvec,
    const float* __restrict__ obp, float* __restrict__ out)
{
  const int wave = threadIdx.x >> 6, lane = threadIdx.x & 63;
  const int b = blockIdx.x*4 + wave;
  union { uint4 q; u16 s[8]; } y;
  y.q = *(const uint4*)&Y2[(size_t)b*H2_SZ + lane*8];
  float4 wa = *(const float4*)&wvec[lane*8];
  float4 wb = *(const float4*)&wvec[lane*8+4];
  float wv[8] = {wa.x,wa.y,wa.z,wa.w,wb.x,wb.y,wb.z,wb.w};
  float s = 0.f;
  #pragma unroll
  for (int j=0;j<8;j++) s += b2f(y.s[j]) * wv[j];
  s += __shfl_xor(s,1);  s += __shfl_xor(s,2);  s += __shfl_xor(s,4);
  s += __shfl_xor(s,8);  s += __shfl_xor(s,16); s += __shfl_xor(s,32);
  if (lane == 0){
    float x = s + obp[0];
    out[b] = 1.f / (1.f + expf(-x));
  }
}

// ---------------- workspace map (bytes) ----------------
// embT @ 0          : 134217728   (dead after k_lp; reused:)
//   z1 @ 0          :  67108864   (fp32 pre-BN layer0)
//   y1 @ 67108864   :  33554432   (bf16 post-BN layer0)
//   z2 @ 100663296  :  33554432   (fp32 pre-BN layer1)
// lzf  @ 134217728  :  33554432   fp32, ZEROED (dead after k_lp; reused as y2 bf16)
// WlT  @ 167772160  :   4194304
// y0   @ 171966464  :  16777216   (bf16, bias-centered)
// W0T  @ 188743680  :   1048576
// W1T  @ 189792256  :   1048576
// stats@ 190840832  : 16 KB ZEROED: S1a[1024] S2a[1024] S1b[512] S2b[512] cvec[1024]
//                     then A0[1024] B0[1024] A1[512] B1[512]
// pqT  @ 190873600  :     65536
// total ~ 191 MB

extern "C" void kernel_launch(void* const* d_in, const int* in_sizes, int n_in,
                              void* d_out, int out_size, void* d_ws, size_t ws_size,
                              hipStream_t stream)
{
  const int*   fidx  = (const int*)d_in[0];
  const float* fval  = (const float*)d_in[1];
  const float* femb  = (const float*)d_in[2];
  const float* wl    = (const float*)d_in[3];
  const float* pbias = (const float*)d_in[4];
  const float* pq    = (const float*)d_in[5];
  const float* w0    = (const float*)d_in[6];
  const float* b0    = (const float*)d_in[7];
  const float* w1    = (const float*)d_in[8];
  const float* b1    = (const float*)d_in[9];
  const float* bnsc  = (const float*)d_in[10];
  const float* bnof  = (const float*)d_in[11];
  const float* ow    = (const float*)d_in[12];
  const float* ob    = (const float*)d_in[13];
  float* out = (float*)d_out;

  char* ws = (char*)d_ws;
  u16*   embT = (u16*)(ws + 0);
  float* z1b  = (float*)(ws + 0);
  u16*   y1b  = (u16*)(ws + 67108864);
  float* z2b  = (float*)(ws + 100663296);
  float* lzf  = (float*)(ws + 134217728);
  u16*   y2b  = (u16*)(ws + 134217728);
  u16*   wlT  = (u16*)(ws + 167772160);
  u16*   y0b  = (u16*)(ws + 171966464);
  u16*   w0T  = (u16*)(ws + 188743680);
  u16*   w1T  = (u16*)(ws + 189792256);
  float* S1a  = (float*)(ws + 190840832);
  float* S2a  = S1a + 1024;
  float* S1b  = S2a + 1024;
  float* S2b  = S1b + 512;
  float* cvec = S2b + 512;
  float* A0   = cvec + 1024;
  float* B0   = A0 + 1024;
  float* A1   = B0 + 1024;
  float* B1   = A1 + 512;
  u16*   pqT  = (u16*)(ws + 190873600);

  hipMemsetAsync((void*)lzf, 0, 33554432, stream);   // lz fp32 accumulator
  hipMemsetAsync((void*)S1a, 0, 16384, stream);      // S1a,S2a,S1b,S2b,cvec

  k_gather<<<B_SZ, 256, 0, stream>>>(fidx, fval, femb, embT);
  k_wlt<<<D_SZ, 256, 0, stream>>>(wl, wlT);
  k_pqt<<<128, 256, 0, stream>>>(pq, pqT);
  k_transpose<<<2048, 256, 0, stream>>>(w0, w0T, 9, 1024, 524288);   // (512,1024)->(1024,512)
  k_transpose<<<2048, 256, 0, stream>>>(w1, w1T, 10, 512, 524288);   // (1024,512)->(512,1024)
  k_cvec<<<dim3(4,8), 256, 0, stream>>>(pbias, w0, b0, cvec);

  gemm_bt_sk<<<dim3(4,128,2), 256, 0, stream>>>(embT, wlT, lzf, D_SZ, KP);
  k_lp<<<B_SZ/LP_NB, 256, 0, stream>>>(embT, pqT, lzf, pbias, y0b);

  gemm_bt<1,float><<<dim3(8,128), 256, 0, stream>>>(y0b, w0T, z1b, cvec, S1a, S2a,
                                                    B_SZ, H1_SZ, D_SZ);
  k_bnfin<<<4, 256, 0, stream>>>(S1a, S2a, 1024, bnsc, bnof, A0, B0);
  k_bnapply<<<8192, 256, 0, stream>>>(z1b, y1b, A0, B0, 1023);

  gemm_bt<1,float><<<dim3(4,128), 256, 0, stream>>>(y1b, w1T, z2b, b1, S1b, S2b,
                                                    B_SZ, H2_SZ, H1_SZ);
  k_bnfin<<<2, 256, 0, stream>>>(S1b, S2b, 512, bnsc, bnof, A1, B1);
  k_bnapply<<<4096, 256, 0, stream>>>(z2b, y2b, A1, B1, 511);

  k_out<<<4096, 256, 0, stream>>>(y2b, ow, ob, out);
}

// Round 6
// 501.267 us; speedup vs baseline: 1.0955x; 1.0955x over previous
//
#include <hip/hip_runtime.h>

typedef unsigned short u16;
typedef __attribute__((ext_vector_type(8))) short bf16x8v;
typedef __attribute__((ext_vector_type(4))) float f32x4v;

#define B_SZ 16384
#define F_SZ 50
#define E_SZ 64
#define D_SZ 512
#define H1_SZ 1024
#define H2_SZ 512
#define KP 4096   // padded product-layer K: (e*64+f), f padded 50->64

__device__ __forceinline__ float b2f(u16 u){
  union { unsigned int i; float f; } v; v.i = ((unsigned int)u) << 16; return v.f;
}
__device__ __forceinline__ u16 f2b(float f){
  union { float f; unsigned int i; } v; v.f = f;
  unsigned int r = v.i + 0x7FFFu + ((v.i >> 16) & 1u);
  return (u16)(r >> 16);
}

// async global->LDS, 16B/lane. g is per-lane (base + lane*16B); lds base is
// wave-uniform; HW writes lds_base + lane*16.
__device__ __forceinline__ void gload16(const u16* g, u16* lds_base_uniform){
#if __has_builtin(__builtin_amdgcn_global_load_lds)
  __builtin_amdgcn_global_load_lds(
      (const __attribute__((address_space(1))) unsigned int*)g,
      (__attribute__((address_space(3))) unsigned int*)lds_base_uniform,
      16, 0, 0);
#else
  int lane = threadIdx.x & 63;
  *(uint4*)(lds_base_uniform + lane*8) = *(const uint4*)g;
#endif
}

// ---------------- gather: embT[b][e*64+f] = fe[idx[b,f],e]*fv[b,f] (bf16), f>=50 -> 0
__global__ __launch_bounds__(256) void k_gather(
    const int* __restrict__ fidx, const float* __restrict__ fval,
    const float* __restrict__ femb, u16* __restrict__ embT)
{
  __shared__ int   sidx[F_SZ];
  __shared__ float sfv[F_SZ];
  __shared__ u16   tile[F_SZ*66];   // padded stride 66 to break bank conflicts
  const int b = blockIdx.x, t = threadIdx.x;
  if (t < F_SZ){ sidx[t] = fidx[b*F_SZ+t]; sfv[t] = fval[b*F_SZ+t]; }
  __syncthreads();
  #pragma unroll
  for (int i=0;i<13;i++){
    int k = i*256+t;
    if (k < F_SZ*E_SZ){
      int f = k>>6, e = k&63;
      tile[f*66+e] = f2b(femb[(size_t)sidx[f]*E_SZ + e] * sfv[f]);
    }
  }
  __syncthreads();
  u16* orow = embT + (size_t)b*KP;
  #pragma unroll
  for (int i=0;i<16;i++){
    int k = i*256+t;           // k = e*64+f
    int f = k&63, e = k>>6;
    orow[k] = (f < F_SZ) ? tile[f*66+e] : (u16)0;
  }
}

// ---------------- product_linear (D,F,E) fp32 -> WlT (D, e*64+f) bf16 zero-padded
__global__ __launch_bounds__(256) void k_wlt(const float* __restrict__ Wl, u16* __restrict__ WlT)
{
  __shared__ u16 tile[F_SZ*66];
  const int d = blockIdx.x, t = threadIdx.x;
  #pragma unroll
  for (int i=0;i<13;i++){
    int k = i*256+t;
    if (k < F_SZ*E_SZ) tile[(k>>6)*66 + (k&63)] = f2b(Wl[(size_t)d*(F_SZ*E_SZ) + k]);
  }
  __syncthreads();
  u16* orow = WlT + (size_t)d*KP;
  #pragma unroll
  for (int i=0;i<16;i++){
    int k = i*256+t;
    int f = k&63, e = k>>6;
    orow[k] = (f < F_SZ) ? tile[f*66+e] : (u16)0;
  }
}

// ---------------- product_quadratic_inner (D,F) fp32 -> PqTp (D,64) bf16 padded
__global__ void k_pqt(const float* __restrict__ Pq, u16* __restrict__ PqTp){
  int idx = blockIdx.x*256 + threadIdx.x;   // grid 128 -> 32768
  int d = idx >> 6, f = idx & 63;
  PqTp[idx] = (f < F_SZ) ? f2b(Pq[d*F_SZ + f]) : (u16)0;
}

// ---------------- (K,N) fp32 -> (N,K) bf16 transpose for dense weights
__global__ void k_transpose(const float* __restrict__ W, u16* __restrict__ WT,
                            int klog2, int N, int total){
  int idx = blockIdx.x*256 + threadIdx.x;
  if (idx < total){
    int k = idx & ((1<<klog2)-1), n = idx >> klog2;
    WT[idx] = f2b(W[(size_t)k*N + n]);
  }
}

// ---------------- cvec[h] += sum_{d in chunk} pbias[d]*W0[d][h] (+ b0[h] once)
// grid (4, 8), block 256; cvec pre-zeroed by memset.
__global__ __launch_bounds__(256) void k_cvec(
    const float* __restrict__ pb, const float* __restrict__ W0,
    const float* __restrict__ b0, float* __restrict__ cvec)
{
  int h = blockIdx.x*256 + threadIdx.x;
  int d0 = blockIdx.y*64;
  float acc = (blockIdx.y == 0) ? b0[h] : 0.f;
  #pragma unroll 8
  for (int d=0; d<64; d++) acc += pb[d0+d]*W0[(size_t)(d0+d)*H1_SZ + h];
  atomicAdd(&cvec[h], acc);
}

// ---------------- fused product layer: per 128b x 128d tile, one pass over
// embT computes BOTH lz (K=4096 GEMM vs WlT) and lp (per e-chunk S_e GEMM vs
// register-resident Pq fragments, squared and accumulated). Each 64-wide
// K-chunk at k0=e*64 is exactly one e-slice, so As serves both contractions.
// Epilogue: y0 = relu(lz + sqrt(lp) + pbias) - pbias   (bias-centered bf16).
__global__ __launch_bounds__(256) void k_prod(
    const u16* __restrict__ A,     // embT (B, KP)
    const u16* __restrict__ Bm,    // WlT  (D, KP)
    const u16* __restrict__ Pp,    // PqTp (D, 64)
    const float* __restrict__ pbias,
    u16* __restrict__ y0)          // (B, D)
{
  __shared__ __align__(16) u16 As[128*64];
  __shared__ __align__(16) u16 Bs[128*64];
  const int tid  = threadIdx.x;
  const int wave = tid >> 6, lane = tid & 63;
  const int quad = lane >> 4, l16 = lane & 15;
  const int n0 = blockIdx.x * 128, m0 = blockIdx.y * 128;
  const int wr = wave >> 1, wc = wave & 1;
  const int lr = lane >> 3, lc = (lane & 7) * 8;

  // loop-invariant P fragments: B-operand rows = d, k = f (ks*32+quad*8)
  bf16x8v pfr[4][2];
  #pragma unroll
  for (int nt=0;nt<4;nt++)
    #pragma unroll
    for (int ks=0;ks<2;ks++)
      pfr[nt][ks] = *(const bf16x8v*)&Pp[(n0 + wc*64 + nt*16 + l16)*64 + ks*32 + quad*8];

  f32x4v acc[4][4];   // lz accumulator
  f32x4v lpa[4][4];   // sum over e of S_e^2
  #pragma unroll
  for (int i=0;i<4;i++)
    #pragma unroll
    for (int j=0;j<4;j++){
      acc[i][j] = (f32x4v){0.f,0.f,0.f,0.f};
      lpa[i][j] = (f32x4v){0.f,0.f,0.f,0.f};
    }
  const f32x4v zz = {0.f,0.f,0.f,0.f};

  for (int k0 = 0; k0 < KP; k0 += 64){
    __syncthreads();
    #pragma unroll
    for (int c=0;c<4;c++){
      const int r0 = wave*32 + 8*c;          // 8 rows per 16B-call
      gload16(A  + (size_t)(m0 + r0 + lr)*KP + k0 + lc, As + r0*64);
      gload16(Bm + (size_t)(n0 + r0 + lr)*KP + k0 + lc, Bs + r0*64);
    }
    __syncthreads();

    bf16x8v af[2][4];
    #pragma unroll
    for (int ks=0;ks<2;ks++)
      #pragma unroll
      for (int mt=0;mt<4;mt++)
        af[ks][mt] = *(const bf16x8v*)&As[(wr*64+mt*16+l16)*64 + ks*32 + quad*8];

    // lz: C += A * WlT^T over this chunk
    #pragma unroll
    for (int ks=0; ks<2; ks++){
      bf16x8v bfr[4];
      #pragma unroll
      for (int nt=0;nt<4;nt++)
        bfr[nt] = *(const bf16x8v*)&Bs[(wc*64+nt*16+l16)*64 + ks*32 + quad*8];
      #pragma unroll
      for (int mt=0;mt<4;mt++)
        #pragma unroll
        for (int nt=0;nt<4;nt++)
          acc[mt][nt] = __builtin_amdgcn_mfma_f32_16x16x32_bf16(af[ks][mt], bfr[nt], acc[mt][nt], 0, 0, 0);
    }

    // lp: S_e = A_chunk * Pq^T (K=64), then lpa += S_e .* S_e
    #pragma unroll
    for (int nt=0;nt<4;nt++){
      f32x4v s[4];
      #pragma unroll
      for (int mt=0;mt<4;mt++)
        s[mt] = __builtin_amdgcn_mfma_f32_16x16x32_bf16(af[0][mt], pfr[nt][0], zz, 0, 0, 0);
      #pragma unroll
      for (int mt=0;mt<4;mt++)
        s[mt] = __builtin_amdgcn_mfma_f32_16x16x32_bf16(af[1][mt], pfr[nt][1], s[mt], 0, 0, 0);
      #pragma unroll
      for (int mt=0;mt<4;mt++)
        #pragma unroll
        for (int r=0;r<4;r++)
          lpa[mt][nt][r] = fmaf(s[mt][r], s[mt][r], lpa[mt][nt][r]);
    }
  }

  // epilogue; C/D layout: n = lane&15, m = quad*4 + reg
  #pragma unroll
  for (int nt=0;nt<4;nt++){
    const int n = n0 + wc*64 + nt*16 + l16;
    const float bv = pbias[n];
    #pragma unroll
    for (int mt=0;mt<4;mt++){
      const int mb = m0 + wr*64 + mt*16 + quad*4;
      #pragma unroll
      for (int r=0;r<4;r++){
        float v = acc[mt][nt][r] + sqrtf(lpa[mt][nt][r]) + bv;
        v = (v > 0.f ? v : 0.f) - bv;
        y0[(size_t)(mb+r)*D_SZ + n] = f2b(v);
      }
    }
  }
}

// ---------------- m97-style BT GEMM: C(MxN) = A(MxK) * Bm(NxK)^T, bf16 inputs
// DO_STATS: add fp32 bias[n], atomically accumulate per-column sum/sumsq.
template<int DO_STATS, typename CT>
__global__ __launch_bounds__(256) void gemm_bt(
    const u16* __restrict__ A, const u16* __restrict__ Bm,
    CT* __restrict__ C, const float* __restrict__ bias,
    float* __restrict__ S1, float* __restrict__ S2,
    int M, int N, int K)
{
  __shared__ __align__(16) u16 As[128*64];
  __shared__ __align__(16) u16 Bs[128*64];
  const int tid  = threadIdx.x;
  const int wave = tid >> 6, lane = tid & 63;
  const int quad = lane >> 4, l16 = lane & 15;
  const int n0 = blockIdx.x * 128, m0 = blockIdx.y * 128;
  const int wr = wave >> 1, wc = wave & 1;
  const int lr = lane >> 3, lc = (lane & 7) * 8;

  f32x4v acc[4][4];
  #pragma unroll
  for (int i=0;i<4;i++)
    #pragma unroll
    for (int j=0;j<4;j++)
      acc[i][j] = (f32x4v){0.f,0.f,0.f,0.f};

  for (int k0 = 0; k0 < K; k0 += 64){
    __syncthreads();
    #pragma unroll
    for (int c=0;c<4;c++){
      const int r0 = wave*32 + 8*c;          // 8 rows per 16B-call
      gload16(A  + (size_t)(m0 + r0 + lr)*K + k0 + lc, As + r0*64);
      gload16(Bm + (size_t)(n0 + r0 + lr)*K + k0 + lc, Bs + r0*64);
    }
    __syncthreads();
    #pragma unroll
    for (int ks=0; ks<2; ks++){
      bf16x8v af[4], bfr[4];
      #pragma unroll
      for (int mt=0;mt<4;mt++)
        af[mt] = *(const bf16x8v*)&As[(wr*64+mt*16+l16)*64 + ks*32 + quad*8];
      #pragma unroll
      for (int nt=0;nt<4;nt++)
        bfr[nt] = *(const bf16x8v*)&Bs[(wc*64+nt*16+l16)*64 + ks*32 + quad*8];
      #pragma unroll
      for (int mt=0;mt<4;mt++)
        #pragma unroll
        for (int nt=0;nt<4;nt++)
          acc[mt][nt] = __builtin_amdgcn_mfma_f32_16x16x32_bf16(af[mt], bfr[nt], acc[mt][nt], 0, 0, 0);
    }
  }

  // epilogue; C/D layout: n = lane&15, m = quad*4 + reg
  #pragma unroll
  for (int nt=0;nt<4;nt++){
    const int n = n0 + wc*64 + nt*16 + l16;
    float bv = 0.f;
    if (DO_STATS) bv = bias[n];
    float ls1 = 0.f, ls2 = 0.f;
    #pragma unroll
    for (int mt=0;mt<4;mt++){
      const int mb = m0 + wr*64 + mt*16 + quad*4;
      #pragma unroll
      for (int r=0;r<4;r++){
        float v = acc[mt][nt][r] + bv;
        if constexpr (sizeof(CT) == 2) C[(size_t)(mb+r)*N + n] = f2b(v);
        else                           C[(size_t)(mb+r)*N + n] = v;
        ls1 += v; ls2 += v*v;
      }
    }
    if (DO_STATS){
      ls1 += __shfl_xor(ls1, 16); ls2 += __shfl_xor(ls2, 16);
      ls1 += __shfl_xor(ls1, 32); ls2 += __shfl_xor(ls2, 32);
      if (quad == 0){ atomicAdd(&S1[n], ls1); atomicAdd(&S2[n], ls2); }
    }
  }
}

// ---------------- BN finalize: per-column scale/offset from sums
__global__ void k_bnfin(const float* __restrict__ S1, const float* __restrict__ S2, int n,
                        const float* __restrict__ bnsc, const float* __restrict__ bnof,
                        float* __restrict__ Aout, float* __restrict__ Bout)
{
  int i = blockIdx.x*256 + threadIdx.x;
  if (i < n){
    const float invB = 1.f / 16384.f;
    float m   = S1[i]*invB;
    float var = S2[i]*invB - m*m;
    float a   = bnsc[0] * rsqrtf(var + 1e-10f);
    Aout[i] = a;
    Bout[i] = bnof[0] - m*a;
  }
}

// ---------------- BN apply + relu: fp32 Z in, bf16 Y out, 8 elems/thread
__global__ __launch_bounds__(256) void k_bnapply(
    const float* __restrict__ Z, u16* __restrict__ Y,
    const float* __restrict__ Aa, const float* __restrict__ Bb, int nmask)
{
  size_t base = ((size_t)blockIdx.x*256 + threadIdx.x) * 8;
  int n0 = (int)(base & (size_t)nmask);
  float4 za = *(const float4*)&Z[base];
  float4 zb = *(const float4*)&Z[base+4];
  float zz[8] = {za.x,za.y,za.z,za.w,zb.x,zb.y,zb.z,zb.w};
  union { uint4 q; u16 s[8]; } o;
  #pragma unroll
  for (int j=0;j<8;j++){
    float v = zz[j] * Aa[n0+j] + Bb[n0+j];
    o.s[j] = f2b(v > 0.f ? v : 0.f);
  }
  *(uint4*)&Y[base] = o.q;
}

// ---------------- final dot + sigmoid, one wave per row; fp32 w and out
__global__ __launch_bounds__(256) void k_out(
    const u16* __restrict__ Y2, const float* __restrict__ wvec,
    const float* __restrict__ obp, float* __restrict__ out)
{
  const int wave = threadIdx.x >> 6, lane = threadIdx.x & 63;
  const int b = blockIdx.x*4 + wave;
  union { uint4 q; u16 s[8]; } y;
  y.q = *(const uint4*)&Y2[(size_t)b*H2_SZ + lane*8];
  float4 wa = *(const float4*)&wvec[lane*8];
  float4 wb = *(const float4*)&wvec[lane*8+4];
  float wv[8] = {wa.x,wa.y,wa.z,wa.w,wb.x,wb.y,wb.z,wb.w};
  float s = 0.f;
  #pragma unroll
  for (int j=0;j<8;j++) s += b2f(y.s[j]) * wv[j];
  s += __shfl_xor(s,1);  s += __shfl_xor(s,2);  s += __shfl_xor(s,4);
  s += __shfl_xor(s,8);  s += __shfl_xor(s,16); s += __shfl_xor(s,32);
  if (lane == 0){
    float x = s + obp[0];
    out[b] = 1.f / (1.f + expf(-x));
  }
}

// ---------------- workspace map (bytes) ----------------
// embT @ 0          : 134217728   (dead after k_prod; reused:)
//   z1 @ 0          :  67108864   (fp32 pre-BN layer0)
//   y1 @ 67108864   :  33554432   (bf16 post-BN layer0)
//   z2 @ 100663296  :  33554432   (fp32 pre-BN layer1)
// WlT  @ 134217728  :   4194304   (dead after k_prod)
// y0   @ 138412032  :  16777216   (bf16, bias-centered)
// W0T  @ 155189248  :   1048576
// W1T  @ 156237824  :   1048576
// y2   @ 157286400  :  16777216   (bf16 post-BN layer1)
// stats@ 174063616  : 16 KB ZEROED: S1a[1024] S2a[1024] S1b[512] S2b[512] cvec[1024]
//                     then A0[1024] B0[1024] A1[512] B1[512]
// pqT  @ 174096384  :     65536
// total ~ 174.2 MB

extern "C" void kernel_launch(void* const* d_in, const int* in_sizes, int n_in,
                              void* d_out, int out_size, void* d_ws, size_t ws_size,
                              hipStream_t stream)
{
  const int*   fidx  = (const int*)d_in[0];
  const float* fval  = (const float*)d_in[1];
  const float* femb  = (const float*)d_in[2];
  const float* wl    = (const float*)d_in[3];
  const float* pbias = (const float*)d_in[4];
  const float* pq    = (const float*)d_in[5];
  const float* w0    = (const float*)d_in[6];
  const float* b0    = (const float*)d_in[7];
  const float* w1    = (const float*)d_in[8];
  const float* b1    = (const float*)d_in[9];
  const float* bnsc  = (const float*)d_in[10];
  const float* bnof  = (const float*)d_in[11];
  const float* ow    = (const float*)d_in[12];
  const float* ob    = (const float*)d_in[13];
  float* out = (float*)d_out;

  char* ws = (char*)d_ws;
  u16*   embT = (u16*)(ws + 0);
  float* z1b  = (float*)(ws + 0);
  u16*   y1b  = (u16*)(ws + 67108864);
  float* z2b  = (float*)(ws + 100663296);
  u16*   wlT  = (u16*)(ws + 134217728);
  u16*   y0b  = (u16*)(ws + 138412032);
  u16*   w0T  = (u16*)(ws + 155189248);
  u16*   w1T  = (u16*)(ws + 156237824);
  u16*   y2b  = (u16*)(ws + 157286400);
  float* S1a  = (float*)(ws + 174063616);
  float* S2a  = S1a + 1024;
  float* S1b  = S2a + 1024;
  float* S2b  = S1b + 512;
  float* cvec = S2b + 512;
  float* A0   = cvec + 1024;
  float* B0   = A0 + 1024;
  float* A1   = B0 + 1024;
  float* B1   = A1 + 512;
  u16*   pqT  = (u16*)(ws + 174096384);

  hipMemsetAsync((void*)S1a, 0, 16384, stream);      // S1a,S2a,S1b,S2b,cvec

  k_gather<<<B_SZ, 256, 0, stream>>>(fidx, fval, femb, embT);
  k_wlt<<<D_SZ, 256, 0, stream>>>(wl, wlT);
  k_pqt<<<128, 256, 0, stream>>>(pq, pqT);
  k_transpose<<<2048, 256, 0, stream>>>(w0, w0T, 9, 1024, 524288);   // (512,1024)->(1024,512)
  k_transpose<<<2048, 256, 0, stream>>>(w1, w1T, 10, 512, 524288);   // (1024,512)->(512,1024)
  k_cvec<<<dim3(4,8), 256, 0, stream>>>(pbias, w0, b0, cvec);

  k_prod<<<dim3(4,128), 256, 0, stream>>>(embT, wlT, pqT, pbias, y0b);

  gemm_bt<1,float><<<dim3(8,128), 256, 0, stream>>>(y0b, w0T, z1b, cvec, S1a, S2a,
                                                    B_SZ, H1_SZ, D_SZ);
  k_bnfin<<<4, 256, 0, stream>>>(S1a, S2a, 1024, bnsc, bnof, A0, B0);
  k_bnapply<<<8192, 256, 0, stream>>>(z1b, y1b, A0, B0, 1023);

  gemm_bt<1,float><<<dim3(4,128), 256, 0, stream>>>(y1b, w1T, z2b, b1, S1b, S2b,
                                                    B_SZ, H2_SZ, H1_SZ);
  k_bnfin<<<2, 256, 0, stream>>>(S1b, S2b, 512, bnsc, bnof, A1, B1);
  k_bnapply<<<4096, 256, 0, stream>>>(z2b, y2b, A1, B1, 511);

  k_out<<<4096, 256, 0, stream>>>(y2b, ow, ob, out);
}

// Round 7
// 498.683 us; speedup vs baseline: 1.1012x; 1.0052x over previous
//
#include <hip/hip_runtime.h>

typedef unsigned short u16;
typedef __attribute__((ext_vector_type(8))) short bf16x8v;
typedef __attribute__((ext_vector_type(4))) float f32x4v;

#define B_SZ 16384
#define F_SZ 50
#define E_SZ 64
#define D_SZ 512
#define H1_SZ 1024
#define H2_SZ 512
#define KP 4096   // padded product-layer K: (e*64+f), f padded 50->64

__device__ __forceinline__ float b2f(u16 u){
  union { unsigned int i; float f; } v; v.i = ((unsigned int)u) << 16; return v.f;
}
__device__ __forceinline__ u16 f2b(float f){
  union { float f; unsigned int i; } v; v.f = f;
  unsigned int r = v.i + 0x7FFFu + ((v.i >> 16) & 1u);
  return (u16)(r >> 16);
}

// async global->LDS, 16B/lane. g is per-lane (base + lane*16B); lds base is
// wave-uniform; HW writes lds_base + lane*16.
__device__ __forceinline__ void gload16(const u16* g, u16* lds_base_uniform){
#if __has_builtin(__builtin_amdgcn_global_load_lds)
  __builtin_amdgcn_global_load_lds(
      (const __attribute__((address_space(1))) unsigned int*)g,
      (__attribute__((address_space(3))) unsigned int*)lds_base_uniform,
      16, 0, 0);
#else
  int lane = threadIdx.x & 63;
  *(uint4*)(lds_base_uniform + lane*8) = *(const uint4*)g;
#endif
}

// ---------------- gather: embT[b][e*64+f] = fe[idx[b,f],e]*fv[b,f] (bf16), f>=50 -> 0
__global__ __launch_bounds__(256) void k_gather(
    const int* __restrict__ fidx, const float* __restrict__ fval,
    const float* __restrict__ femb, u16* __restrict__ embT)
{
  __shared__ int   sidx[F_SZ];
  __shared__ float sfv[F_SZ];
  __shared__ u16   tile[F_SZ*66];   // padded stride 66 to break bank conflicts
  const int b = blockIdx.x, t = threadIdx.x;
  if (t < F_SZ){ sidx[t] = fidx[b*F_SZ+t]; sfv[t] = fval[b*F_SZ+t]; }
  __syncthreads();
  #pragma unroll
  for (int i=0;i<13;i++){
    int k = i*256+t;
    if (k < F_SZ*E_SZ){
      int f = k>>6, e = k&63;
      tile[f*66+e] = f2b(femb[(size_t)sidx[f]*E_SZ + e] * sfv[f]);
    }
  }
  __syncthreads();
  u16* orow = embT + (size_t)b*KP;
  #pragma unroll
  for (int i=0;i<16;i++){
    int k = i*256+t;           // k = e*64+f
    int f = k&63, e = k>>6;
    orow[k] = (f < F_SZ) ? tile[f*66+e] : (u16)0;
  }
}

// ---------------- product_linear (D,F,E) fp32 -> WlT (D, e*64+f) bf16 zero-padded
__global__ __launch_bounds__(256) void k_wlt(const float* __restrict__ Wl, u16* __restrict__ WlT)
{
  __shared__ u16 tile[F_SZ*66];
  const int d = blockIdx.x, t = threadIdx.x;
  #pragma unroll
  for (int i=0;i<13;i++){
    int k = i*256+t;
    if (k < F_SZ*E_SZ) tile[(k>>6)*66 + (k&63)] = f2b(Wl[(size_t)d*(F_SZ*E_SZ) + k]);
  }
  __syncthreads();
  u16* orow = WlT + (size_t)d*KP;
  #pragma unroll
  for (int i=0;i<16;i++){
    int k = i*256+t;
    int f = k&63, e = k>>6;
    orow[k] = (f < F_SZ) ? tile[f*66+e] : (u16)0;
  }
}

// ---------------- product_quadratic_inner (D,F) fp32 -> PqTp (D,64) bf16 padded
__global__ void k_pqt(const float* __restrict__ Pq, u16* __restrict__ PqTp){
  int idx = blockIdx.x*256 + threadIdx.x;   // grid 128 -> 32768
  int d = idx >> 6, f = idx & 63;
  PqTp[idx] = (f < F_SZ) ? f2b(Pq[d*F_SZ + f]) : (u16)0;
}

// ---------------- (K,N) fp32 -> (N,K) bf16 transpose for dense weights
__global__ void k_transpose(const float* __restrict__ W, u16* __restrict__ WT,
                            int klog2, int N, int total){
  int idx = blockIdx.x*256 + threadIdx.x;
  if (idx < total){
    int k = idx & ((1<<klog2)-1), n = idx >> klog2;
    WT[idx] = f2b(W[(size_t)k*N + n]);
  }
}

// ---------------- cvec[h] += sum_{d in chunk} pbias[d]*W0[d][h] (+ b0[h] once)
// grid (4, 8), block 256; cvec pre-zeroed by memset.
__global__ __launch_bounds__(256) void k_cvec(
    const float* __restrict__ pb, const float* __restrict__ W0,
    const float* __restrict__ b0, float* __restrict__ cvec)
{
  int h = blockIdx.x*256 + threadIdx.x;
  int d0 = blockIdx.y*64;
  float acc = (blockIdx.y == 0) ? b0[h] : 0.f;
  #pragma unroll 8
  for (int d=0; d<64; d++) acc += pb[d0+d]*W0[(size_t)(d0+d)*H1_SZ + h];
  atomicAdd(&cvec[h], acc);
}

// ---------------- fused product layer, v2: 512 threads, 128b x 128d tile.
// Each wave owns a 32m x 64n subtile (mt=2, nt=4) -> acc+lpa = 64 accum regs
// (vs 128 in v1, which forced 1 wave/SIMD). One pass over embT computes BOTH
// lz (GEMM vs WlT) and lp (per e-chunk S_e vs register-resident Pq frags,
// squared, accumulated). Epilogue: y0 = relu(lz+sqrt(lp)+pbias)-pbias.
__global__ __launch_bounds__(512) void k_prod(
    const u16* __restrict__ A,     // embT (B, KP)
    const u16* __restrict__ Bm,    // WlT  (D, KP)
    const u16* __restrict__ Pp,    // PqTp (D, 64)
    const float* __restrict__ pbias,
    u16* __restrict__ y0)          // (B, D)
{
  __shared__ __align__(16) u16 As[128*64];
  __shared__ __align__(16) u16 Bs[128*64];
  const int tid  = threadIdx.x;
  const int wave = tid >> 6, lane = tid & 63;
  const int quad = lane >> 4, l16 = lane & 15;
  const int n0 = blockIdx.x * 128, m0 = blockIdx.y * 128;
  const int wr = wave >> 1, wc = wave & 1;   // wr 0..3 (32 m-rows), wc 0..1 (64 n)
  const int lr = lane >> 3, lc = (lane & 7) * 8;

  // loop-invariant P fragments: rows = d, k = f
  bf16x8v pfr[4][2];
  #pragma unroll
  for (int nt=0;nt<4;nt++)
    #pragma unroll
    for (int ks=0;ks<2;ks++)
      pfr[nt][ks] = *(const bf16x8v*)&Pp[(n0 + wc*64 + nt*16 + l16)*64 + ks*32 + quad*8];

  f32x4v acc[2][4];   // lz accumulator
  f32x4v lpa[2][4];   // sum over e of S_e^2
  #pragma unroll
  for (int i=0;i<2;i++)
    #pragma unroll
    for (int j=0;j<4;j++){
      acc[i][j] = (f32x4v){0.f,0.f,0.f,0.f};
      lpa[i][j] = (f32x4v){0.f,0.f,0.f,0.f};
    }
  const f32x4v zz = {0.f,0.f,0.f,0.f};

  for (int k0 = 0; k0 < KP; k0 += 64){
    __syncthreads();
    // 8 waves stage As(128 rows) + Bs(128 rows): 2+2 gload16 calls per wave
    #pragma unroll
    for (int c=0;c<2;c++){
      const int r0 = (wave + c*8) * 8;       // 8 rows per 16B-call
      gload16(A  + (size_t)(m0 + r0 + lr)*KP + k0 + lc, As + r0*64);
      gload16(Bm + (size_t)(n0 + r0 + lr)*KP + k0 + lc, Bs + r0*64);
    }
    __syncthreads();

    bf16x8v af[2][2];
    #pragma unroll
    for (int ks=0;ks<2;ks++)
      #pragma unroll
      for (int mt=0;mt<2;mt++)
        af[ks][mt] = *(const bf16x8v*)&As[(wr*32+mt*16+l16)*64 + ks*32 + quad*8];

    // lz: C += A * WlT^T over this chunk
    #pragma unroll
    for (int ks=0; ks<2; ks++){
      bf16x8v bfr[4];
      #pragma unroll
      for (int nt=0;nt<4;nt++)
        bfr[nt] = *(const bf16x8v*)&Bs[(wc*64+nt*16+l16)*64 + ks*32 + quad*8];
      #pragma unroll
      for (int mt=0;mt<2;mt++)
        #pragma unroll
        for (int nt=0;nt<4;nt++)
          acc[mt][nt] = __builtin_amdgcn_mfma_f32_16x16x32_bf16(af[ks][mt], bfr[nt], acc[mt][nt], 0, 0, 0);
    }

    // lp: S_e = A_chunk * Pq^T (K=64), then lpa += S_e .* S_e
    #pragma unroll
    for (int nt=0;nt<4;nt++){
      f32x4v s[2];
      #pragma unroll
      for (int mt=0;mt<2;mt++)
        s[mt] = __builtin_amdgcn_mfma_f32_16x16x32_bf16(af[0][mt], pfr[nt][0], zz, 0, 0, 0);
      #pragma unroll
      for (int mt=0;mt<2;mt++)
        s[mt] = __builtin_amdgcn_mfma_f32_16x16x32_bf16(af[1][mt], pfr[nt][1], s[mt], 0, 0, 0);
      #pragma unroll
      for (int mt=0;mt<2;mt++)
        #pragma unroll
        for (int r=0;r<4;r++)
          lpa[mt][nt][r] = fmaf(s[mt][r], s[mt][r], lpa[mt][nt][r]);
    }
  }

  // epilogue; C/D layout: n = lane&15, m = quad*4 + reg
  #pragma unroll
  for (int nt=0;nt<4;nt++){
    const int n = n0 + wc*64 + nt*16 + l16;
    const float bv = pbias[n];
    #pragma unroll
    for (int mt=0;mt<2;mt++){
      const int mb = m0 + wr*32 + mt*16 + quad*4;
      #pragma unroll
      for (int r=0;r<4;r++){
        float v = acc[mt][nt][r] + sqrtf(lpa[mt][nt][r]) + bv;
        v = (v > 0.f ? v : 0.f) - bv;
        y0[(size_t)(mb+r)*D_SZ + n] = f2b(v);
      }
    }
  }
}

// ---------------- m97-style BT GEMM: C(MxN) = A(MxK) * Bm(NxK)^T, bf16 inputs
// DO_STATS: add fp32 bias[n], atomically accumulate per-column sum/sumsq.
template<int DO_STATS, typename CT>
__global__ __launch_bounds__(256) void gemm_bt(
    const u16* __restrict__ A, const u16* __restrict__ Bm,
    CT* __restrict__ C, const float* __restrict__ bias,
    float* __restrict__ S1, float* __restrict__ S2,
    int M, int N, int K)
{
  __shared__ __align__(16) u16 As[128*64];
  __shared__ __align__(16) u16 Bs[128*64];
  const int tid  = threadIdx.x;
  const int wave = tid >> 6, lane = tid & 63;
  const int quad = lane >> 4, l16 = lane & 15;
  const int n0 = blockIdx.x * 128, m0 = blockIdx.y * 128;
  const int wr = wave >> 1, wc = wave & 1;
  const int lr = lane >> 3, lc = (lane & 7) * 8;

  f32x4v acc[4][4];
  #pragma unroll
  for (int i=0;i<4;i++)
    #pragma unroll
    for (int j=0;j<4;j++)
      acc[i][j] = (f32x4v){0.f,0.f,0.f,0.f};

  for (int k0 = 0; k0 < K; k0 += 64){
    __syncthreads();
    #pragma unroll
    for (int c=0;c<4;c++){
      const int r0 = wave*32 + 8*c;          // 8 rows per 16B-call
      gload16(A  + (size_t)(m0 + r0 + lr)*K + k0 + lc, As + r0*64);
      gload16(Bm + (size_t)(n0 + r0 + lr)*K + k0 + lc, Bs + r0*64);
    }
    __syncthreads();
    #pragma unroll
    for (int ks=0; ks<2; ks++){
      bf16x8v af[4], bfr[4];
      #pragma unroll
      for (int mt=0;mt<4;mt++)
        af[mt] = *(const bf16x8v*)&As[(wr*64+mt*16+l16)*64 + ks*32 + quad*8];
      #pragma unroll
      for (int nt=0;nt<4;nt++)
        bfr[nt] = *(const bf16x8v*)&Bs[(wc*64+nt*16+l16)*64 + ks*32 + quad*8];
      #pragma unroll
      for (int mt=0;mt<4;mt++)
        #pragma unroll
        for (int nt=0;nt<4;nt++)
          acc[mt][nt] = __builtin_amdgcn_mfma_f32_16x16x32_bf16(af[mt], bfr[nt], acc[mt][nt], 0, 0, 0);
    }
  }

  // epilogue; C/D layout: n = lane&15, m = quad*4 + reg
  #pragma unroll
  for (int nt=0;nt<4;nt++){
    const int n = n0 + wc*64 + nt*16 + l16;
    float bv = 0.f;
    if (DO_STATS) bv = bias[n];
    float ls1 = 0.f, ls2 = 0.f;
    #pragma unroll
    for (int mt=0;mt<4;mt++){
      const int mb = m0 + wr*64 + mt*16 + quad*4;
      #pragma unroll
      for (int r=0;r<4;r++){
        float v = acc[mt][nt][r] + bv;
        if constexpr (sizeof(CT) == 2) C[(size_t)(mb+r)*N + n] = f2b(v);
        else                           C[(size_t)(mb+r)*N + n] = v;
        ls1 += v; ls2 += v*v;
      }
    }
    if (DO_STATS){
      ls1 += __shfl_xor(ls1, 16); ls2 += __shfl_xor(ls2, 16);
      ls1 += __shfl_xor(ls1, 32); ls2 += __shfl_xor(ls2, 32);
      if (quad == 0){ atomicAdd(&S1[n], ls1); atomicAdd(&S2[n], ls2); }
    }
  }
}

// ---------------- BN finalize: per-column scale/offset from sums
__global__ void k_bnfin(const float* __restrict__ S1, const float* __restrict__ S2, int n,
                        const float* __restrict__ bnsc, const float* __restrict__ bnof,
                        float* __restrict__ Aout, float* __restrict__ Bout)
{
  int i = blockIdx.x*256 + threadIdx.x;
  if (i < n){
    const float invB = 1.f / 16384.f;
    float m   = S1[i]*invB;
    float var = S2[i]*invB - m*m;
    float a   = bnsc[0] * rsqrtf(var + 1e-10f);
    Aout[i] = a;
    Bout[i] = bnof[0] - m*a;
  }
}

// ---------------- BN apply + relu: fp32 Z in, bf16 Y out, 8 elems/thread
__global__ __launch_bounds__(256) void k_bnapply(
    const float* __restrict__ Z, u16* __restrict__ Y,
    const float* __restrict__ Aa, const float* __restrict__ Bb, int nmask)
{
  size_t base = ((size_t)blockIdx.x*256 + threadIdx.x) * 8;
  int n0 = (int)(base & (size_t)nmask);
  float4 za = *(const float4*)&Z[base];
  float4 zb = *(const float4*)&Z[base+4];
  float zz[8] = {za.x,za.y,za.z,za.w,zb.x,zb.y,zb.z,zb.w};
  union { uint4 q; u16 s[8]; } o;
  #pragma unroll
  for (int j=0;j<8;j++){
    float v = zz[j] * Aa[n0+j] + Bb[n0+j];
    o.s[j] = f2b(v > 0.f ? v : 0.f);
  }
  *(uint4*)&Y[base] = o.q;
}

// ---------------- final dot + sigmoid, one wave per row; fp32 w and out
__global__ __launch_bounds__(256) void k_out(
    const u16* __restrict__ Y2, const float* __restrict__ wvec,
    const float* __restrict__ obp, float* __restrict__ out)
{
  const int wave = threadIdx.x >> 6, lane = threadIdx.x & 63;
  const int b = blockIdx.x*4 + wave;
  union { uint4 q; u16 s[8]; } y;
  y.q = *(const uint4*)&Y2[(size_t)b*H2_SZ + lane*8];
  float4 wa = *(const float4*)&wvec[lane*8];
  float4 wb = *(const float4*)&wvec[lane*8+4];
  float wv[8] = {wa.x,wa.y,wa.z,wa.w,wb.x,wb.y,wb.z,wb.w};
  float s = 0.f;
  #pragma unroll
  for (int j=0;j<8;j++) s += b2f(y.s[j]) * wv[j];
  s += __shfl_xor(s,1);  s += __shfl_xor(s,2);  s += __shfl_xor(s,4);
  s += __shfl_xor(s,8);  s += __shfl_xor(s,16); s += __shfl_xor(s,32);
  if (lane == 0){
    float x = s + obp[0];
    out[b] = 1.f / (1.f + expf(-x));
  }
}

// ---------------- workspace map (bytes) ----------------
// embT @ 0          : 134217728   (dead after k_prod; reused:)
//   z1 @ 0          :  67108864   (fp32 pre-BN layer0)
//   y1 @ 67108864   :  33554432   (bf16 post-BN layer0)
//   z2 @ 100663296  :  33554432   (fp32 pre-BN layer1)
// WlT  @ 134217728  :   4194304   (dead after k_prod)
// y0   @ 138412032  :  16777216   (bf16, bias-centered)
// W0T  @ 155189248  :   1048576
// W1T  @ 156237824  :   1048576
// y2   @ 157286400  :  16777216   (bf16 post-BN layer1)
// stats@ 174063616  : 16 KB ZEROED: S1a[1024] S2a[1024] S1b[512] S2b[512] cvec[1024]
//                     then A0[1024] B0[1024] A1[512] B1[512]
// pqT  @ 174096384  :     65536
// total ~ 174.2 MB

extern "C" void kernel_launch(void* const* d_in, const int* in_sizes, int n_in,
                              void* d_out, int out_size, void* d_ws, size_t ws_size,
                              hipStream_t stream)
{
  const int*   fidx  = (const int*)d_in[0];
  const float* fval  = (const float*)d_in[1];
  const float* femb  = (const float*)d_in[2];
  const float* wl    = (const float*)d_in[3];
  const float* pbias = (const float*)d_in[4];
  const float* pq    = (const float*)d_in[5];
  const float* w0    = (const float*)d_in[6];
  const float* b0    = (const float*)d_in[7];
  const float* w1    = (const float*)d_in[8];
  const float* b1    = (const float*)d_in[9];
  const float* bnsc  = (const float*)d_in[10];
  const float* bnof  = (const float*)d_in[11];
  const float* ow    = (const float*)d_in[12];
  const float* ob    = (const float*)d_in[13];
  float* out = (float*)d_out;

  char* ws = (char*)d_ws;
  u16*   embT = (u16*)(ws + 0);
  float* z1b  = (float*)(ws + 0);
  u16*   y1b  = (u16*)(ws + 67108864);
  float* z2b  = (float*)(ws + 100663296);
  u16*   wlT  = (u16*)(ws + 134217728);
  u16*   y0b  = (u16*)(ws + 138412032);
  u16*   w0T  = (u16*)(ws + 155189248);
  u16*   w1T  = (u16*)(ws + 156237824);
  u16*   y2b  = (u16*)(ws + 157286400);
  float* S1a  = (float*)(ws + 174063616);
  float* S2a  = S1a + 1024;
  float* S1b  = S2a + 1024;
  float* S2b  = S1b + 512;
  float* cvec = S2b + 512;
  float* A0   = cvec + 1024;
  float* B0   = A0 + 1024;
  float* A1   = B0 + 1024;
  float* B1   = A1 + 512;
  u16*   pqT  = (u16*)(ws + 174096384);

  hipMemsetAsync((void*)S1a, 0, 16384, stream);      // S1a,S2a,S1b,S2b,cvec

  k_gather<<<B_SZ, 256, 0, stream>>>(fidx, fval, femb, embT);
  k_wlt<<<D_SZ, 256, 0, stream>>>(wl, wlT);
  k_pqt<<<128, 256, 0, stream>>>(pq, pqT);
  k_transpose<<<2048, 256, 0, stream>>>(w0, w0T, 9, 1024, 524288);   // (512,1024)->(1024,512)
  k_transpose<<<2048, 256, 0, stream>>>(w1, w1T, 10, 512, 524288);   // (1024,512)->(512,1024)
  k_cvec<<<dim3(4,8), 256, 0, stream>>>(pbias, w0, b0, cvec);

  k_prod<<<dim3(4,128), 512, 0, stream>>>(embT, wlT, pqT, pbias, y0b);

  gemm_bt<1,float><<<dim3(8,128), 256, 0, stream>>>(y0b, w0T, z1b, cvec, S1a, S2a,
                                                    B_SZ, H1_SZ, D_SZ);
  k_bnfin<<<4, 256, 0, stream>>>(S1a, S2a, 1024, bnsc, bnof, A0, B0);
  k_bnapply<<<8192, 256, 0, stream>>>(z1b, y1b, A0, B0, 1023);

  gemm_bt<1,float><<<dim3(4,128), 256, 0, stream>>>(y1b, w1T, z2b, b1, S1b, S2b,
                                                    B_SZ, H2_SZ, H1_SZ);
  k_bnfin<<<2, 256, 0, stream>>>(S1b, S2b, 512, bnsc, bnof, A1, B1);
  k_bnapply<<<4096, 256, 0, stream>>>(z2b, y2b, A1, B1, 511);

  k_out<<<4096, 256, 0, stream>>>(y2b, ow, ob, out);
}